// Round 1
// baseline (374.284 us; speedup 1.0000x reference)
//
#include <hip/hip_runtime.h>
#include <math.h>

#define N 256
#define MKRY 40
#define MAXCYC 3

// Build C[a][b] = S[b][a] = P[b][a] - P[a][b]  (i.e. C row j holds S[:, j]^T,
// so z_i = sum_j S[i][j] u_j reads C[j*N + i] coalesced in i).
__global__ __launch_bounds__(1024) void build_C_kernel(const float* __restrict__ P,
                                                       float* __restrict__ C) {
    __shared__ float ta[32][33];
    __shared__ float tb[32][33];
    const int tx = threadIdx.x, ty = threadIdx.y;
    const int r0 = blockIdx.y * 32, c0 = blockIdx.x * 32;
    ta[ty][tx] = P[(r0 + ty) * N + (c0 + tx)];
    tb[ty][tx] = P[(c0 + ty) * N + (r0 + tx)];
    __syncthreads();
    // C[r0+ty][c0+tx] = P[c0+tx][r0+ty] - P[r0+ty][c0+tx]
    C[(r0 + ty) * N + (c0 + tx)] = tb[tx][ty] - ta[ty][tx];
}

__device__ __forceinline__ float block_sum256(float v, float* red, int lane, int wave) {
    v += __shfl_down(v, 32);
    v += __shfl_down(v, 16);
    v += __shfl_down(v, 8);
    v += __shfl_down(v, 4);
    v += __shfl_down(v, 2);
    v += __shfl_down(v, 1);
    __syncthreads();               // protect red[] from previous use
    if (lane == 0) red[wave] = v;
    __syncthreads();
    return red[0] + red[1] + red[2] + red[3];
}

template <bool HAS_WS>
__device__ __forceinline__ float matvec_row(const float* __restrict__ C,
                                            const float* __restrict__ P,
                                            const float* __restrict__ us, int tid) {
    // returns (S * us)[tid]
    float acc = 0.f;
    if (HAS_WS) {
#pragma unroll 8
        for (int j = 0; j < N; ++j) acc = fmaf(C[j * N + tid], us[j], acc);
    } else {
#pragma unroll 4
        for (int j = 0; j < N; ++j)
            acc = fmaf(P[tid * N + j] - P[j * N + tid], us[j], acc);
    }
    return acc;
}

// One block per (b,t): solve (I + S diag(x)) w = v by GMRES(MKRY) with up to
// MAXCYC restart cycles, CGS2 orthogonalization. out = 2w - v.
template <bool HAS_WS>
__global__ __launch_bounds__(256) void cayley_solve(const float* __restrict__ x_all,
                                                    const float* __restrict__ P,
                                                    const float* __restrict__ v_in,
                                                    const float* __restrict__ C,
                                                    float* __restrict__ out) {
    __shared__ float V[(MKRY + 1) * N];
    __shared__ float Rm[MKRY * MKRY];
    __shared__ float xs[N], vs[N], us[N], zs[N], wv[N];
    __shared__ float hc1[MKRY + 2], hc2[MKRY + 2];
    __shared__ float cs[MKRY], sn[MKRY], gg[MKRY + 1], yy[MKRY];
    __shared__ float red[4];
    __shared__ int iflag[1];

    const int tid = threadIdx.x;
    const int lane = tid & 63, wave = tid >> 6;
    const int b = blockIdx.x;

    xs[tid] = x_all[b * N + tid];
    vs[tid] = v_in[tid];
    wv[tid] = 0.f;
    __syncthreads();

    float tol = 0.f;
    for (int cycle = 0; cycle < MAXCYC; ++cycle) {
        // r = v - A w,  A w = w + S (x .* w)
        us[tid] = xs[tid] * wv[tid];
        __syncthreads();
        float rt = vs[tid] - wv[tid] - matvec_row<HAS_WS>(C, P, us, tid);
        float beta = sqrtf(block_sum256(rt * rt, red, lane, wave));
        if (cycle == 0) tol = fmaxf(1e-5f * beta, 1e-30f);
        if (beta <= tol) break;

        V[tid] = rt / beta;
        if (tid == 0) { gg[0] = beta; iflag[0] = 0; }
        __syncthreads();

        int k = 0;
        for (int j = 0; j < MKRY; ++j) {
            // z = A V[j]
            us[tid] = xs[tid] * V[j * N + tid];
            __syncthreads();
            float zt = V[j * N + tid] + matvec_row<HAS_WS>(C, P, us, tid);

            // --- CGS pass 1: hc1 = V^T z ---
            zs[tid] = zt;
            __syncthreads();
            for (int i = wave; i <= j; i += 4) {
                float s = 0.f;
#pragma unroll
                for (int c = 0; c < 4; ++c)
                    s = fmaf(V[i * N + lane + 64 * c], zs[lane + 64 * c], s);
                s += __shfl_down(s, 32); s += __shfl_down(s, 16); s += __shfl_down(s, 8);
                s += __shfl_down(s, 4);  s += __shfl_down(s, 2);  s += __shfl_down(s, 1);
                if (lane == 0) hc1[i] = s;
            }
            __syncthreads();
            for (int i = 0; i <= j; ++i) zt = fmaf(-hc1[i], V[i * N + tid], zt);

            // --- CGS pass 2 (reorthogonalize) ---
            zs[tid] = zt;
            __syncthreads();
            for (int i = wave; i <= j; i += 4) {
                float s = 0.f;
#pragma unroll
                for (int c = 0; c < 4; ++c)
                    s = fmaf(V[i * N + lane + 64 * c], zs[lane + 64 * c], s);
                s += __shfl_down(s, 32); s += __shfl_down(s, 16); s += __shfl_down(s, 8);
                s += __shfl_down(s, 4);  s += __shfl_down(s, 2);  s += __shfl_down(s, 1);
                if (lane == 0) hc2[i] = s;
            }
            __syncthreads();
            for (int i = 0; i <= j; ++i) zt = fmaf(-hc2[i], V[i * N + tid], zt);
            if (tid <= j) hc1[tid] += hc2[tid];  // ordered by syncs inside block_sum256

            float hjp1 = sqrtf(block_sum256(zt * zt, red, lane, wave));
            float invh = (hjp1 > 1e-30f) ? 1.f / hjp1 : 0.f;
            V[(j + 1) * N + tid] = zt * invh;

            if (tid == 0) {
                // apply previous Givens rotations to column hc1[0..j]
                for (int i = 0; i < j; ++i) {
                    float t0 = cs[i] * hc1[i] + sn[i] * hc1[i + 1];
                    hc1[i + 1] = -sn[i] * hc1[i] + cs[i] * hc1[i + 1];
                    hc1[i] = t0;
                }
                float a0 = hc1[j], b0 = hjp1;
                float r0 = sqrtf(a0 * a0 + b0 * b0);
                float c0 = 1.f, s0 = 0.f;
                if (r0 > 1e-30f) { c0 = a0 / r0; s0 = b0 / r0; }
                cs[j] = c0; sn[j] = s0;
                for (int i = 0; i < j; ++i) Rm[i * MKRY + j] = hc1[i];
                Rm[j * MKRY + j] = r0;
                gg[j + 1] = -s0 * gg[j];
                gg[j] = c0 * gg[j];
                if (fabsf(gg[j + 1]) <= tol) iflag[0] = 1;
            }
            __syncthreads();
            k = j + 1;
            if (iflag[0]) break;
        }

        // back-substitute R y = g (serial, small)
        if (tid == 0) {
            for (int i = k - 1; i >= 0; --i) {
                float s = gg[i];
                for (int l = i + 1; l < k; ++l) s -= Rm[i * MKRY + l] * yy[l];
                float d = Rm[i * MKRY + i];
                yy[i] = (fabsf(d) > 1e-30f) ? s / d : 0.f;
            }
        }
        __syncthreads();
        float wt = wv[tid];
        for (int i = 0; i < k; ++i) wt = fmaf(yy[i], V[i * N + tid], wt);
        wv[tid] = wt;
        __syncthreads();
    }

    out[b * N + tid] = 2.f * wv[tid] - vs[tid];
}

extern "C" void kernel_launch(void* const* d_in, const int* in_sizes, int n_in,
                              void* d_out, int out_size, void* d_ws, size_t ws_size,
                              hipStream_t stream) {
    const float* x = (const float*)d_in[0];       // (B*T, 256)
    const float* P = (const float*)d_in[1];       // skew_param (256,256)
    const float* v = (const float*)d_in[2];       // (1,256)
    float* out = (float*)d_out;
    const int batch = in_sizes[0] / N;            // B*T = 1024

    const bool has_ws = ws_size >= (size_t)(N * N * sizeof(float));
    if (has_ws) {
        float* C = (float*)d_ws;
        hipLaunchKernelGGL(build_C_kernel, dim3(N / 32, N / 32), dim3(32, 32), 0, stream,
                           P, C);
        hipLaunchKernelGGL((cayley_solve<true>), dim3(batch), dim3(N), 0, stream,
                           x, P, v, C, out);
    } else {
        hipLaunchKernelGGL((cayley_solve<false>), dim3(batch), dim3(N), 0, stream,
                           x, P, v, (const float*)nullptr, out);
    }
}

// Round 2
// 230.900 us; speedup vs baseline: 1.6210x; 1.6210x over previous
//
#include <hip/hip_runtime.h>
#include <math.h>

#define N 256
#define G 4
#define BLK 1024
#define M 22          // Krylov dim per refinement sweep
#define MAXCYC 4
#define SROW 264      // padded f16 row stride (multiple of 8 for b128 alignment)
#define U32ROW 260

typedef _Float16 half2v __attribute__((ext_vector_type(2)));
typedef unsigned int uint4v __attribute__((ext_vector_type(4)));

#if defined(__has_builtin)
#if __has_builtin(__builtin_amdgcn_fdot2)
#define HAVE_FDOT2 1
#endif
#endif

// Module-scope scratch (no hipMalloc; rebuilt every launch, graph-capture safe).
__device__ __align__(16) float g_C32[N * N];      // C32[a][b] = S[b][a]
__device__ __align__(16) _Float16 g_S16[N * N];   // row-major S, f16

__device__ __forceinline__ float fdot2p(unsigned int a, unsigned int b, float acc) {
    half2v ah = __builtin_bit_cast(half2v, a);
    half2v bh = __builtin_bit_cast(half2v, b);
#ifdef HAVE_FDOT2
    return __builtin_amdgcn_fdot2(ah, bh, acc, false);
#else
    return fmaf((float)ah.x, (float)bh.x, fmaf((float)ah.y, (float)bh.y, acc));
#endif
}

// Build S (f16, row-major) and S^T (fp32) from P:  S = P - P^T.
__global__ __launch_bounds__(1024) void build_mats(const float* __restrict__ P) {
    __shared__ float ta[32][33];
    __shared__ float tb[32][33];
    const int tx = threadIdx.x, ty = threadIdx.y;
    const int r0 = blockIdx.y * 32, c0 = blockIdx.x * 32;
    ta[ty][tx] = P[(r0 + ty) * N + (c0 + tx)];
    tb[ty][tx] = P[(c0 + ty) * N + (r0 + tx)];
    __syncthreads();
    float s = ta[ty][tx] - tb[tx][ty];            // S[r0+ty][c0+tx]
    g_C32[(r0 + ty) * N + (c0 + tx)] = -s;        // C32[a][b] = S[b][a]
    g_S16[(r0 + ty) * N + (c0 + tx)] = (_Float16)s;
}

// Reduce p over the 16 c-values in each wave (lanes tid = c*4 + g), leaving
// per-(wave,g) partials in part[slot][wave][g].
__device__ __forceinline__ void red_write(float p, int slot, float part[][16][G], int tid) {
    p += __shfl_down(p, 4);
    p += __shfl_down(p, 8);
    p += __shfl_down(p, 16);
    p += __shfl_down(p, 32);
    if ((tid & 63) < 4) part[slot][tid >> 6][tid & 3] = p;
}

__device__ __forceinline__ void red_final(const float part[][16][G], float dst[][G],
                                          int nslots, int tid) {
    if (tid < 4 * nslots) {
        const int i = tid >> 2, gq = tid & 3;
        float s = 0.f;
#pragma unroll
        for (int wv = 0; wv < 16; ++wv) s += part[i][wv][gq];
        dst[i][gq] = s;
    }
}

// One block = 4 systems (I + S diag(x)) w = v, solved by f16-matvec GMRES(M)
// wrapped in fp32 iterative refinement. out = 2w - v.
__global__ __launch_bounds__(BLK, 4) void cayley_ms(const float* __restrict__ x_all,
                                                    const float* __restrict__ v_in,
                                                    float* __restrict__ out, int batch) {
    __shared__ _Float16 sS[N * SROW];            // 135168 B: S rows, f16, padded
    __shared__ _Float16 sU[G * SROW];            // f16 x.*q per system
    __shared__ float sU32[G * U32ROW];           // fp32 x.*w for outer residual
    __shared__ float sPart[M + 1][16][G];
    __shared__ float sH1[M + 1][G];
    __shared__ float sH2[M + 1][G];
    __shared__ float sRm[G][M][M];
    __shared__ float sCs[G][M], sSn[G][M], sGg[G][M + 1], sYy[G][M];
    __shared__ float sNorm[G];
    __shared__ float sTolIn[G];
    __shared__ float sFlagF[G];

    const int tid = threadIdx.x;
    const int c = tid >> 2, g = tid & 3;
    const int sys = blockIdx.x * G + g;
    const bool alive = sys < batch;

    // ---- stage f16 S into padded LDS (coalesced uint4 loads) ----
    {
        const uint4v* gS = (const uint4v*)g_S16;
#pragma unroll
        for (int it = 0; it < 8; ++it) {
            int idx = it * BLK + tid;            // uint4 index; 32 per row
            int row = idx >> 5;
            int colp = (idx & 31) << 3;          // f16 column (multiple of 8)
            *(uint4v*)(&sS[row * SROW + colp]) = gS[idx];
        }
    }

    const float x_own = alive ? x_all[sys * N + c] : 0.f;
    const float v_own = v_in[c];
    float w = 0.f;
    float Vv[M + 1];
    float tol_out = 0.f;
    __syncthreads();

    for (int cyc = 0; cyc < MAXCYC; ++cyc) {
        // ---- fp32 residual r = v - w - S(x.*w) (streams C32 from L2) ----
        float r;
        if (cyc == 0) {
            r = alive ? v_own : 0.f;             // w == 0
        } else {
            sU32[g * U32ROW + c] = x_own * w;
            __syncthreads();
            float acc = 0.f;
#pragma unroll 8
            for (int j = 0; j < N; ++j)
                acc = fmaf(g_C32[j * N + c], sU32[g * U32ROW + j], acc);
            r = alive ? (v_own - w - acc) : 0.f;
            __syncthreads();
        }

        red_write(r * r, 0, sPart, tid);
        __syncthreads();
        if (tid < 4) {
            float s = 0.f;
#pragma unroll
            for (int wv = 0; wv < 16; ++wv) s += sPart[0][wv][tid];
            sNorm[tid] = s;
        }
        __syncthreads();
        const float beta = sqrtf(sNorm[g]);
        if (cyc == 0) tol_out = fmaxf(2e-5f * beta, 1e-30f);
        if (tid < 4) {
            sFlagF[tid] = (beta <= tol_out) ? 1.f : 0.f;  // tid<4 -> g==tid
            sTolIn[tid] = fmaxf(0.0035f * beta, 0.5f * tol_out);
        }
        __syncthreads();
        if (sFlagF[0] + sFlagF[1] + sFlagF[2] + sFlagF[3] == 4.f) break;

        const float ib = (beta > 1e-30f) ? 1.f / beta : 0.f;
        Vv[0] = r * ib;
        if (tid < 4) sGg[tid][0] = beta;

        // ---- inner f16-matvec GMRES(M) on the correction equation ----
        int k = 0;
        for (int j = 0; j < M; ++j) {
            float q = 0.f;
#pragma unroll
            for (int i = 0; i < M; ++i)
                if (i == j) q = Vv[i];

            sU[g * SROW + c] = (_Float16)(x_own * q);
            __syncthreads();                                     // A

            float a0 = 0.f, a1 = 0.f, a2 = 0.f, a3 = 0.f;
            {
                const uint4v* srow = (const uint4v*)(&sS[c * SROW]);
                const uint4v* urow = (const uint4v*)(&sU[g * SROW]);
#pragma unroll 4
                for (int p = 0; p < 32; ++p) {
                    uint4v aa = srow[p];
                    uint4v bb = urow[p];
                    a0 = fdot2p(aa.x, bb.x, a0);
                    a1 = fdot2p(aa.y, bb.y, a1);
                    a2 = fdot2p(aa.z, bb.z, a2);
                    a3 = fdot2p(aa.w, bb.w, a3);
                }
            }
            float z = q + ((a0 + a1) + (a2 + a3));               // (A q)_c

            // CGS pass 1
#pragma unroll
            for (int i = 0; i < M; ++i)
                if (i <= j) red_write(Vv[i] * z, i, sPart, tid);
            __syncthreads();                                     // B
            red_final(sPart, sH1, j + 1, tid);
            __syncthreads();                                     // C
#pragma unroll
            for (int i = 0; i < M; ++i)
                if (i <= j) z = fmaf(-sH1[i][g], Vv[i], z);

            // CGS pass 2
#pragma unroll
            for (int i = 0; i < M; ++i)
                if (i <= j) red_write(Vv[i] * z, i, sPart, tid);
            __syncthreads();                                     // D
            red_final(sPart, sH2, j + 1, tid);
            __syncthreads();                                     // E
#pragma unroll
            for (int i = 0; i < M; ++i)
                if (i <= j) z = fmaf(-sH2[i][g], Vv[i], z);

            // ||z||
            red_write(z * z, M, sPart, tid);
            __syncthreads();                                     // F
            if (tid < 4) {
                float s = 0.f;
#pragma unroll
                for (int wv = 0; wv < 16; ++wv) s += sPart[M][wv][tid];
                sNorm[tid] = s;
            }
            __syncthreads();                                     // G
            const float hj = sqrtf(sNorm[g]);
            const float iv = (hj > 1e-30f) ? 1.f / hj : 0.f;
#pragma unroll
            for (int i = 1; i <= M; ++i)
                if (i == j + 1) Vv[i] = z * iv;

            if (tid < 4) {
                const int gq = tid;
                for (int i = 0; i <= j; ++i) sH1[i][gq] += sH2[i][gq];
                for (int i = 0; i < j; ++i) {
                    float ai = sH1[i][gq], bi = sH1[i + 1][gq];
                    float cc = sCs[gq][i], ss = sSn[gq][i];
                    sH1[i][gq] = cc * ai + ss * bi;
                    sH1[i + 1][gq] = -ss * ai + cc * bi;
                }
                float aj = sH1[j][gq];
                float bj = sqrtf(sNorm[gq]);
                float rr = sqrtf(aj * aj + bj * bj);
                float cc = 1.f, ss = 0.f;
                if (rr > 1e-30f) { cc = aj / rr; ss = bj / rr; }
                sCs[gq][j] = cc;
                sSn[gq][j] = ss;
                for (int i = 0; i < j; ++i) sRm[gq][i][j] = sH1[i][gq];
                sRm[gq][j][j] = rr;
                float gj = sGg[gq][j];
                float gn = -ss * gj;
                sGg[gq][j + 1] = gn;
                sGg[gq][j] = cc * gj;
                sFlagF[gq] = fabsf(gn);
            }
            __syncthreads();                                     // H
            k = j + 1;
            if (sFlagF[0] <= sTolIn[0] && sFlagF[1] <= sTolIn[1] &&
                sFlagF[2] <= sTolIn[2] && sFlagF[3] <= sTolIn[3])
                break;
        }

        // back-substitute R y = g
        if (tid < 4) {
            const int gq = tid;
            for (int i = k - 1; i >= 0; --i) {
                float s = sGg[gq][i];
                for (int l = i + 1; l < k; ++l) s -= sRm[gq][i][l] * sYy[gq][l];
                float d = sRm[gq][i][i];
                sYy[gq][i] = (fabsf(d) > 1e-30f) ? s / d : 0.f;
            }
        }
        __syncthreads();
#pragma unroll
        for (int i = 0; i < M; ++i)
            if (i < k) w = fmaf(sYy[g][i], Vv[i], w);
        __syncthreads();
    }

    if (alive) out[sys * N + c] = 2.f * w - v_own;
}

extern "C" void kernel_launch(void* const* d_in, const int* in_sizes, int n_in,
                              void* d_out, int out_size, void* d_ws, size_t ws_size,
                              hipStream_t stream) {
    const float* x = (const float*)d_in[0];   // (B*T, 256)
    const float* P = (const float*)d_in[1];   // skew_param (256,256)
    const float* v = (const float*)d_in[2];   // (1,256)
    float* out = (float*)d_out;
    const int batch = in_sizes[0] / N;        // B*T

    hipLaunchKernelGGL(build_mats, dim3(N / 32, N / 32), dim3(32, 32), 0, stream, P);
    const int nblk = (batch + G - 1) / G;
    hipLaunchKernelGGL(cayley_ms, dim3(nblk), dim3(BLK), 0, stream, x, v, out, batch);
}

// Round 3
// 216.451 us; speedup vs baseline: 1.7292x; 1.0668x over previous
//
#include <hip/hip_runtime.h>
#include <math.h>

#define N 256
#define G 4
#define BLK 1024
#define M 18          // Krylov dim per refinement sweep
#define MAXSW 4       // max IR sweeps
#define SROW 264      // padded f16 row stride (keeps b128 alignment, breaks bank stride)
#define U32ROW 260

typedef _Float16 half2v __attribute__((ext_vector_type(2)));
typedef _Float16 half8v __attribute__((ext_vector_type(8)));
typedef unsigned int uint4v __attribute__((ext_vector_type(4)));
typedef float float4v __attribute__((ext_vector_type(4)));

#if defined(__has_builtin)
#if __has_builtin(__builtin_amdgcn_fdot2)
#define HAVE_FDOT2 1
#endif
#endif

__device__ __forceinline__ float fdot2p(unsigned int a, unsigned int b, float acc) {
    half2v ah = __builtin_bit_cast(half2v, a);
    half2v bh = __builtin_bit_cast(half2v, b);
#ifdef HAVE_FDOT2
    return __builtin_amdgcn_fdot2(ah, bh, acc, false);
#else
    return fmaf((float)ah.x, (float)bh.x, fmaf((float)ah.y, (float)bh.y, acc));
#endif
}

// Partial reduce over the 16 c-values per wave (lanes tid = c*4 + g).
__device__ __forceinline__ void red_write(float p, int slot, float part[][16][G], int tid) {
    p += __shfl_down(p, 4);
    p += __shfl_down(p, 8);
    p += __shfl_down(p, 16);
    p += __shfl_down(p, 32);
    if ((tid & 63) < 4) part[slot][tid >> 6][tid & 3] = p;
}

__device__ __forceinline__ void red_final(const float part[][16][G], float dst[][G],
                                          int nslots, int tid) {
    if (tid < 4 * nslots) {
        const int i = tid >> 2, gq = tid & 3;
        float s = 0.f;
#pragma unroll
        for (int wv = 0; wv < 16; ++wv) s += part[i][wv][gq];
        dst[i][gq] = s;
    }
}

// Fused: stage S=P-P^T (f16, LDS), then per block solve G=4 systems
// (I + S diag(x)) w = v via f16-matvec GMRES(M) + fp32 iterative refinement.
// out = 2w - v.  3 __syncthreads per inner iteration; Givens QR runs on
// lanes tid<4 overlapped with the other waves' matvec.
__global__ __launch_bounds__(BLK) void cayley_fused(const float* __restrict__ x_all,
                                                    const float* __restrict__ P,
                                                    const float* __restrict__ v_in,
                                                    float* __restrict__ out, int batch) {
    __shared__ _Float16 sS[N * SROW];          // 135168 B
    __shared__ _Float16 sU[G * SROW];          // f16 x.*q per system
    __shared__ float sU32[G * U32ROW];         // fp32 x.*w for outer residual
    __shared__ float sPart[M + 1][16][G];
    __shared__ float sHcol[M + 2][G];
    __shared__ float sRm[G][M][M];
    __shared__ float sCs[G][M], sSn[G][M], sGg[G][M + 1], sYy[G][M];
    __shared__ float sNorm[G];
    __shared__ float sTolIn[G], sTolOut[G];
    __shared__ float sFlag[G];

    const int tid = threadIdx.x;
    const int c = tid >> 2, g = tid & 3;
    const int sys = blockIdx.x * G + g;
    const bool alive = sys < batch;

    // ---- stage S = P - P^T into LDS as f16 (P is L2-resident: 256 KB) ----
#pragma unroll
    for (int it = 0; it < 8; ++it) {
        const int ch = it * BLK + tid;         // 8192 chunks of 8 f16
        const int row = ch >> 5;
        const int c8 = (ch & 31) << 3;
        const float* pr = P + row * N + c8;
        float4v a0 = *(const float4v*)pr;
        float4v a1 = *(const float4v*)(pr + 4);
        const float* pc = P + c8 * N + row;
        float t0 = pc[0],     t1 = pc[N],     t2 = pc[2 * N], t3 = pc[3 * N];
        float t4 = pc[4 * N], t5 = pc[5 * N], t6 = pc[6 * N], t7 = pc[7 * N];
        half8v h;
        h[0] = (_Float16)(a0.x - t0); h[1] = (_Float16)(a0.y - t1);
        h[2] = (_Float16)(a0.z - t2); h[3] = (_Float16)(a0.w - t3);
        h[4] = (_Float16)(a1.x - t4); h[5] = (_Float16)(a1.y - t5);
        h[6] = (_Float16)(a1.z - t6); h[7] = (_Float16)(a1.w - t7);
        *(half8v*)&sS[row * SROW + c8] = h;
    }

    const float x_own = alive ? x_all[sys * N + c] : 0.f;
    const float v_own = v_in[c];
    float w = 0.f;
    float Vv[M + 1];
    __syncthreads();

    for (int sw = 0; sw < MAXSW; ++sw) {
        // ---- fp32 outer residual r = v - w - S(x.*w), S from global P ----
        float r;
        if (sw == 0) {
            r = alive ? v_own : 0.f;
        } else {
            sU32[g * U32ROW + c] = x_own * w;
            __syncthreads();
            const float* urow = &sU32[g * U32ROW];
            float ac0 = 0.f, ac1 = 0.f, ac2 = 0.f, ac3 = 0.f;
#pragma unroll 4
            for (int j4 = 0; j4 < N; j4 += 4) {
                float4v pa = *(const float4v*)&P[c * N + j4];
                float q0 = P[(j4 + 0) * N + c];
                float q1 = P[(j4 + 1) * N + c];
                float q2 = P[(j4 + 2) * N + c];
                float q3 = P[(j4 + 3) * N + c];
                float4v uu = *(const float4v*)&urow[j4];
                ac0 = fmaf(pa.x - q0, uu.x, ac0);
                ac1 = fmaf(pa.y - q1, uu.y, ac1);
                ac2 = fmaf(pa.z - q2, uu.z, ac2);
                ac3 = fmaf(pa.w - q3, uu.w, ac3);
            }
            r = alive ? (v_own - w - ((ac0 + ac1) + (ac2 + ac3))) : 0.f;
        }

        red_write(r * r, 0, sPart, tid);
        __syncthreads();
        if (tid < 4) {
            float s = 0.f;
#pragma unroll
            for (int wv = 0; wv < 16; ++wv) s += sPart[0][wv][tid];
            sNorm[tid] = s;
            if (sw == 0) sTolOut[tid] = fmaxf(2e-5f * sqrtf(s), 1e-30f);
        }
        __syncthreads();

        bool allc = true;
#pragma unroll
        for (int q = 0; q < 4; ++q) allc = allc && (sqrtf(sNorm[q]) <= sTolOut[q]);
        if (allc) break;

        const float beta = sqrtf(sNorm[g]);
        const float ib = (beta > 1e-30f) ? 1.f / beta : 0.f;
        Vv[0] = r * ib;
        float qcur = Vv[0];
        sU[g * SROW + c] = (_Float16)(x_own * qcur);
        if (tid < 4) {
            sTolIn[tid] = fmaxf(2.5e-3f * sqrtf(sNorm[tid]), 0.45f * sTolOut[tid]);
            sGg[tid][0] = sqrtf(sNorm[tid]);
            sFlag[tid] = 3.4e38f;
        }

        int k = 0;
        for (int j = 0; j < M; ++j) {
            __syncthreads();                                     // A: sU, sFlag, Givens
            if (sFlag[0] <= sTolIn[0] && sFlag[1] <= sTolIn[1] &&
                sFlag[2] <= sTolIn[2] && sFlag[3] <= sTolIn[3])
                break;

            // z = q + S (x.*q)  (f16 matvec; 4 systems share S rows by broadcast)
            float a0 = 0.f, a1 = 0.f, a2 = 0.f, a3 = 0.f;
            {
                const uint4v* srow = (const uint4v*)&sS[c * SROW];
                const uint4v* urow = (const uint4v*)&sU[g * SROW];
#pragma unroll 4
                for (int p = 0; p < 32; ++p) {
                    uint4v aa = srow[p];
                    uint4v bb = urow[p];
                    a0 = fdot2p(aa.x, bb.x, a0);
                    a1 = fdot2p(aa.y, bb.y, a1);
                    a2 = fdot2p(aa.z, bb.z, a2);
                    a3 = fdot2p(aa.w, bb.w, a3);
                }
            }
            float z = qcur + ((a0 + a1) + (a2 + a3));

            // fused reduction: dots h_i = V_i^T z (i<=j) and ||z||^2 at slot j+1
#pragma unroll
            for (int i = 0; i < M; ++i)
                if (i <= j) red_write(Vv[i] * z, i, sPart, tid);
            red_write(z * z, j + 1, sPart, tid);
            __syncthreads();                                     // B
            red_final(sPart, sHcol, j + 2, tid);
            __syncthreads();                                     // C

            // CGS1 update + Pythagorean norm of the orthogonalized z
            float h2 = 0.f;
#pragma unroll
            for (int i = 0; i < M; ++i)
                if (i <= j) {
                    float hi = sHcol[i][g];
                    z = fmaf(-hi, Vv[i], z);
                    h2 = fmaf(hi, hi, h2);
                }
            const float zn2 = sHcol[j + 1][g];
            const float s2 = fmaxf(zn2 - h2, 1e-8f * zn2);
            const float hj1 = sqrtf(s2);
            const float iv = (hj1 > 1e-30f) ? 1.f / hj1 : 0.f;
            const float vnew = z * iv;
#pragma unroll
            for (int i = 1; i <= M; ++i)
                if (i == j + 1) Vv[i] = vnew;
            qcur = vnew;
            sU[g * SROW + c] = (_Float16)(x_own * vnew);

            // Givens on column j (lanes tid<4; overlaps next iter's matvec)
            if (tid < 4) {
                const int gq = tid;
                float prev = sHcol[0][gq];
                for (int i = 0; i < j; ++i) {
                    float cur = sHcol[i + 1][gq];
                    float cc = sCs[gq][i], ss = sSn[gq][i];
                    sRm[gq][i][j] = fmaf(cc, prev, ss * cur);
                    prev = fmaf(-ss, prev, cc * cur);
                }
                float bj = hj1;
                float rr = sqrtf(fmaf(prev, prev, bj * bj));
                float cc = 1.f, ss = 0.f;
                if (rr > 1e-30f) { cc = prev / rr; ss = bj / rr; }
                sCs[gq][j] = cc;
                sSn[gq][j] = ss;
                sRm[gq][j][j] = rr;
                float gj = sGg[gq][j];
                sGg[gq][j + 1] = -ss * gj;
                sGg[gq][j] = cc * gj;
                sFlag[gq] = fabsf(ss * gj);
            }
            k = j + 1;
        }

        __syncthreads();                                         // D: final Givens visible
        if (tid < 4) {
            const int gq = tid;
            for (int i = k - 1; i >= 0; --i) {
                float s = sGg[gq][i];
                for (int l = i + 1; l < k; ++l) s = fmaf(-sRm[gq][i][l], sYy[gq][l], s);
                float d = sRm[gq][i][i];
                sYy[gq][i] = (fabsf(d) > 1e-30f) ? s / d : 0.f;
            }
        }
        __syncthreads();                                         // E: y visible
#pragma unroll
        for (int i = 0; i < M; ++i)
            if (i < k) w = fmaf(sYy[g][i], Vv[i], w);
    }

    if (alive) out[sys * N + c] = 2.f * w - v_own;
}

extern "C" void kernel_launch(void* const* d_in, const int* in_sizes, int n_in,
                              void* d_out, int out_size, void* d_ws, size_t ws_size,
                              hipStream_t stream) {
    const float* x = (const float*)d_in[0];   // (B*T, 256)
    const float* P = (const float*)d_in[1];   // skew_param (256,256)
    const float* v = (const float*)d_in[2];   // (1,256)
    float* out = (float*)d_out;
    const int batch = in_sizes[0] / N;        // B*T

    const int nblk = (batch + G - 1) / G;
    hipLaunchKernelGGL(cayley_fused, dim3(nblk), dim3(BLK), 0, stream, x, P, v, out, batch);
}

// Round 4
// 138.209 us; speedup vs baseline: 2.7081x; 1.5661x over previous
//
#include <hip/hip_runtime.h>
#include <math.h>

#define N 256
#define G 4
#define BLK 1024
#define M 18          // Krylov dim per refinement sweep
#define MAXSW 4       // max IR sweeps
#define UTS 280       // uT row stride in halfs (560 B: odd multiple of 16B -> 2-way banks)

typedef _Float16 half8v __attribute__((ext_vector_type(8)));
typedef float float4v __attribute__((ext_vector_type(4)));

// ---- LDS arena (bytes). uThi/uTlo rows 4..15 are garbage-read by MFMA B-frags
// (columns 4..15 of the 16-wide tile are never consumed); overlap is harmless.
#define OFF_SLO   0          // 131072: S_lo f16, per-wave fragment-block layout
#define OFF_UTHI  131072     // 4 rows x UTS halfs (2240 B valid, 8960 B read-span)
#define OFF_UTLO  133312
#define OFF_ZTW   135552     // 16 waves x 4 sys x 16 rows f32 (4096)
#define OFF_SPART 139648     // (M+2) x 16 x G f32 (5120)
#define OFF_SHCOL 144768     // (M+2) x G (320)
#define OFF_SRM   145088     // G x M x M (5184)
#define OFF_SCS   150272     // G x M (288)
#define OFF_SSN   150560
#define OFF_SGG   150848     // G x (M+1) (304)
#define OFF_SYY   151152     // G x M (288)
#define OFF_SNORM 151440
#define OFF_STIN  151456
#define OFF_STOUT 151472
#define OFF_SFLAG 151488
#define ARENA_SZ  151552

__device__ __forceinline__ void red_write(float p, int slot, float* part, int tid) {
    p += __shfl_down(p, 4);
    p += __shfl_down(p, 8);
    p += __shfl_down(p, 16);
    p += __shfl_down(p, 32);
    if ((tid & 63) < 4) part[(slot * 16 + (tid >> 6)) * G + (tid & 3)] = p;
}

// B-fragment read: lane provides B[k=8*mq+j][n=mn] of K-block t.
#define LD_FRAG(base, t) (*(const half8v*)((base) + mn * UTS + 32 * (t) + 8 * mq))

__global__ __launch_bounds__(BLK, 4) void cayley_mfma(const float* __restrict__ x_all,
                                                      const float* __restrict__ P,
                                                      const float* __restrict__ v_in,
                                                      float* __restrict__ out, int batch) {
    __shared__ __align__(16) char arena[ARENA_SZ];
    _Float16* sLo   = (_Float16*)(arena + OFF_SLO);
    _Float16* uThi  = (_Float16*)(arena + OFF_UTHI);
    _Float16* uTlo  = (_Float16*)(arena + OFF_UTLO);
    float* zTw      = (float*)(arena + OFF_ZTW);
    float* sPart    = (float*)(arena + OFF_SPART);
    float* sHcol    = (float*)(arena + OFF_SHCOL);   // [i][g] -> i*G+g
    float* sRm      = (float*)(arena + OFF_SRM);     // (g*M+i)*M+l
    float* sCs      = (float*)(arena + OFF_SCS);     // g*M+i
    float* sSn      = (float*)(arena + OFF_SSN);
    float* sGg      = (float*)(arena + OFF_SGG);     // g*(M+1)+i
    float* sYy      = (float*)(arena + OFF_SYY);
    float* sNorm    = (float*)(arena + OFF_SNORM);
    float* sTolIn   = (float*)(arena + OFF_STIN);
    float* sTolOut  = (float*)(arena + OFF_STOUT);
    float* sFlag    = (float*)(arena + OFF_SFLAG);

    const int tid = threadIdx.x;
    const int lane = tid & 63, wv = tid >> 6;
    const int mn = lane & 15, mq = lane >> 4;        // MFMA fragment coords
    const int c = tid >> 2, g = tid & 3;             // solver coords
    const int coff = lane >> 2;                      // c & 15 (wave-local row)
    const int sys = blockIdx.x * G + g;
    const bool alive = sys < batch;

    // ---- preamble: build S = P - P^T as A-fragments. hi(f16)->regs, lo(f16)->LDS.
    // Wave wv owns rows [16*wv, 16*wv+16); P is L2-resident (256 KB).
    half8v Shi[8];
    {
        const int r = 16 * wv + mn;
#pragma unroll
        for (int t = 0; t < 8; ++t) {
            const int k0 = 32 * t + 8 * mq;
            float4v pa = *(const float4v*)(P + r * N + k0);
            float4v pb = *(const float4v*)(P + r * N + k0 + 4);
            float sv[8];
            sv[0] = pa.x; sv[1] = pa.y; sv[2] = pa.z; sv[3] = pa.w;
            sv[4] = pb.x; sv[5] = pb.y; sv[6] = pb.z; sv[7] = pb.w;
            half8v hi, lo;
#pragma unroll
            for (int jj = 0; jj < 8; ++jj) {
                float s = sv[jj] - P[(k0 + jj) * N + r];
                _Float16 h = (_Float16)s;
                hi[jj] = h;
                lo[jj] = (_Float16)(s - (float)h);
            }
            Shi[t] = hi;
            *(half8v*)(sLo + ((wv * 8 + t) * 64 + lane) * 8) = lo;   // intra-wave reuse
        }
    }

    const float x_own = alive ? x_all[sys * N + c] : 0.f;
    const float v_own = v_in[c];
    float wsol = 0.f;
    float Vv[M + 1];
    float qcur = 0.f;

    for (int sw = 0; sw < MAXSW; ++sw) {
        // ---- outer residual r = v - w - S(x.*w), near-fp32 via split f16 MFMA ----
        float r;
        if (sw == 0) {
            r = alive ? v_own : 0.f;
        } else {
            float u = x_own * wsol;
            _Float16 uh = (_Float16)u;
            uThi[g * UTS + c] = uh;
            uTlo[g * UTS + c] = (_Float16)(u - (float)uh);
            __syncthreads();                                          // O1
            float4v acc = {0.f, 0.f, 0.f, 0.f};
#pragma unroll
            for (int t = 0; t < 8; ++t)
                acc = __builtin_amdgcn_mfma_f32_16x16x32_f16(Shi[t], LD_FRAG(uThi, t), acc, 0, 0, 0);
#pragma unroll
            for (int t = 0; t < 8; ++t)
                acc = __builtin_amdgcn_mfma_f32_16x16x32_f16(Shi[t], LD_FRAG(uTlo, t), acc, 0, 0, 0);
#pragma unroll
            for (int t = 0; t < 8; ++t) {
                half8v sl = *(const half8v*)(sLo + ((wv * 8 + t) * 64 + lane) * 8);
                acc = __builtin_amdgcn_mfma_f32_16x16x32_f16(sl, LD_FRAG(uThi, t), acc, 0, 0, 0);
            }
            if (mn < 4) *(float4v*)(zTw + wv * 64 + mn * 16 + mq * 4) = acc;
            float zm = zTw[wv * 64 + g * 16 + coff];                  // intra-wave
            r = alive ? (v_own - wsol - zm) : 0.f;
        }

        red_write(r * r, 0, sPart, tid);
        __syncthreads();                                              // O2
        if (tid < 4) {
            float s = 0.f;
#pragma unroll
            for (int q = 0; q < 16; ++q) s += sPart[q * G + tid];
            sNorm[tid] = s;
            if (sw == 0) sTolOut[tid] = fmaxf(2e-5f * sqrtf(s), 1e-30f);
        }
        __syncthreads();                                              // O3

        bool allc = true;
#pragma unroll
        for (int q = 0; q < 4; ++q) allc = allc && (sqrtf(sNorm[q]) <= sTolOut[q]);
        if (allc) break;

        const float beta = sqrtf(sNorm[g]);
        const float ib = (beta > 1e-30f) ? 1.f / beta : 0.f;
        Vv[0] = r * ib;
        qcur = Vv[0];
        uThi[g * UTS + c] = (_Float16)(x_own * qcur);
        if (tid < 4) {
            sTolIn[tid] = fmaxf(2.5e-3f * sqrtf(sNorm[tid]), 0.45f * sTolOut[tid]);
            sGg[tid * (M + 1)] = sqrtf(sNorm[tid]);
            sFlag[tid] = 3.4e38f;
        }

        // ---- inner GMRES(M): f16 MFMA matvec, fp32 CGS1+Pythagoras ----
        int k = 0;
        for (int j = 0; j < M; ++j) {
            __syncthreads();                                          // A
            if (sFlag[0] <= sTolIn[0] && sFlag[1] <= sTolIn[1] &&
                sFlag[2] <= sTolIn[2] && sFlag[3] <= sTolIn[3])
                break;

            float4v acc = {0.f, 0.f, 0.f, 0.f};
#pragma unroll
            for (int t = 0; t < 8; ++t)
                acc = __builtin_amdgcn_mfma_f32_16x16x32_f16(Shi[t], LD_FRAG(uThi, t), acc, 0, 0, 0);
            if (mn < 4) *(float4v*)(zTw + wv * 64 + mn * 16 + mq * 4) = acc;
            float z = qcur + zTw[wv * 64 + g * 16 + coff];            // intra-wave

            // fused dots h_i = V_i^T z (i<=j) and ||z||^2 at slot j+1
#pragma unroll
            for (int i = 0; i < M; ++i)
                if (i <= j) red_write(Vv[i] * z, i, sPart, tid);
            red_write(z * z, j + 1, sPart, tid);
            __syncthreads();                                          // C
            if (tid < 4 * (j + 2)) {
                const int i = tid >> 2, gq = tid & 3;
                float s = 0.f;
#pragma unroll
                for (int q = 0; q < 16; ++q) s += sPart[(i * 16 + q) * G + gq];
                sHcol[i * G + gq] = s;
            }
            __syncthreads();                                          // D

            float h2 = 0.f;
#pragma unroll
            for (int i = 0; i < M; ++i)
                if (i <= j) {
                    float hi = sHcol[i * G + g];
                    z = fmaf(-hi, Vv[i], z);
                    h2 = fmaf(hi, hi, h2);
                }
            const float zn2 = sHcol[(j + 1) * G + g];
            const float s2 = fmaxf(zn2 - h2, 1e-8f * zn2);
            const float hj1 = sqrtf(s2);
            const float iv = (hj1 > 1e-30f) ? 1.f / hj1 : 0.f;
            const float vnew = z * iv;
#pragma unroll
            for (int i = 1; i <= M; ++i)
                if (i == j + 1) Vv[i] = vnew;
            qcur = vnew;
            uThi[g * UTS + c] = (_Float16)(x_own * vnew);   // readers passed C

            if (tid < 4) {   // Givens col j; overlaps other waves' next matvec
                const int gq = tid;
                float prev = sHcol[gq];
                for (int i = 0; i < j; ++i) {
                    float cur = sHcol[(i + 1) * G + gq];
                    float cc = sCs[gq * M + i], ss = sSn[gq * M + i];
                    sRm[(gq * M + i) * M + j] = fmaf(cc, prev, ss * cur);
                    prev = fmaf(-ss, prev, cc * cur);
                }
                float rr = sqrtf(fmaf(prev, prev, hj1 * hj1));
                float cc = 1.f, ss = 0.f;
                if (rr > 1e-30f) { cc = prev / rr; ss = hj1 / rr; }
                sCs[gq * M + j] = cc;
                sSn[gq * M + j] = ss;
                sRm[(gq * M + j) * M + j] = rr;
                float gj = sGg[gq * (M + 1) + j];
                sGg[gq * (M + 1) + j + 1] = -ss * gj;
                sGg[gq * (M + 1) + j] = cc * gj;
                sFlag[gq] = fabsf(ss * gj);
            }
            k = j + 1;
        }

        __syncthreads();                                              // pre-backsub
        if (tid < 4) {
            const int gq = tid;
            for (int i = k - 1; i >= 0; --i) {
                float s = sGg[gq * (M + 1) + i];
                for (int l = i + 1; l < k; ++l)
                    s = fmaf(-sRm[(gq * M + i) * M + l], sYy[gq * M + l], s);
                float d = sRm[(gq * M + i) * M + i];
                sYy[gq * M + i] = (fabsf(d) > 1e-30f) ? s / d : 0.f;
            }
        }
        __syncthreads();                                              // y visible
#pragma unroll
        for (int i = 0; i < M; ++i)
            if (i < k) wsol = fmaf(sYy[g * M + i], Vv[i], wsol);
    }

    if (alive) out[sys * N + c] = 2.f * wsol - v_own;
}

extern "C" void kernel_launch(void* const* d_in, const int* in_sizes, int n_in,
                              void* d_out, int out_size, void* d_ws, size_t ws_size,
                              hipStream_t stream) {
    const float* x = (const float*)d_in[0];   // (B*T, 256)
    const float* P = (const float*)d_in[1];   // skew_param (256,256)
    const float* v = (const float*)d_in[2];   // (1,256)
    float* out = (float*)d_out;
    const int batch = in_sizes[0] / N;        // B*T

    const int nblk = (batch + G - 1) / G;
    hipLaunchKernelGGL(cayley_mfma, dim3(nblk), dim3(BLK), 0, stream, x, P, v, out, batch);
}